// Round 3
// baseline (507.323 us; speedup 1.0000x reference)
//
#include <hip/hip_runtime.h>
#include <hip/hip_fp16.h>

// DKVMN forward, v20 = v19 with ALL scalar-memory ops removed from the state
//  kernel's hot loop.
//  R2 evidence: SGPR w-prefetch gained only 326->302us; residual ~1400cyc/
//  SIMD-step stall. Root cause: SMEM completes OUT-OF-ORDER, so lgkmcnt
//  cannot wait on a specific s_load clause -> consuming buffer A after
//  issuing buffer B forces lgkmcnt(0), draining the prefetch too. SGPR
//  ping-pong is structurally defeated; every step pays a scalar L2 round
//  trip (~200cyc) for Wh AND for qd/qad.
//  v20: (1) qd/qad staged per-block into LDS once (in-order DS reads,
//  precise lgkm waits, depth-3); (2) Wh row via VMEM uniform-address
//  broadcast loads (6x dwordx4 + 1 dword -> 25 VGPRs), single buffer
//  refilled for t+1 after step-t use (vmcnt is in-order/precise; ~6 resident
//  waves give >=1400cyc of cover for ~250cyc L2); (3) empty asm "+v" pins q
//  in a VGPR so uniformity analysis can't re-scalarize into SMEM.
//  Math bit-identical to v18/v19 (same fdot2+hfma2 order, same w bits).
//  k1 prep : EA {-e,a} f16 | Wt/Wh/Q1 | W1s pack | zero outputs 1..3.
//  k3 mlp_pred : MFMA 16x16x32 bf16 GEMM [B*S,224]@[224,64] + fused epilogue.
// Workspace: Wt 1MB | Q1 1MB | EA 8MB | W1s 32KB | Wh 0.64MB | RD 164MB.

#define NQ1   5001
#define NQA   10001
#define MEMN  50
#define KD    50
#define VD    200
#define FC    50
#define BB    2048
#define SS    200
#define EA_R  16
#define WHS   32       // Wh row stride in u32 (25 pairs + 7 zero pad, 128B)

#define EA_B   626     // ceil(10001/16)
#define WQ_B   1251    // ceil(5001/4)
#define PACK_B 8
#define PREP_G (EA_B + WQ_B + PACK_B)   // 1885 blocks

typedef unsigned int   u32;
typedef unsigned short u16;
typedef short    s8v __attribute__((ext_vector_type(8)));   // 8 bf16 (4 VGPRs)
typedef float    f4v __attribute__((ext_vector_type(4)));   // MFMA C/D
typedef _Float16 h2v __attribute__((ext_vector_type(2)));   // packed f16 pair
typedef u32      u4v __attribute__((ext_vector_type(4)));   // dwordx4

__device__ __forceinline__ float fast_sigmoid(float x) { return 1.f / (1.f + __expf(-x)); }
__device__ __forceinline__ float fast_tanh(float x) {
    float e2 = __expf(2.f * x);           // inf-safe
    return 1.f - 2.f / (e2 + 1.f);
}
__device__ __forceinline__ float bfu16_to_f(u16 u) {
    union { float f; u32 i; } x; x.i = ((u32)u) << 16; return x.f;
}
__device__ __forceinline__ u16 f_to_bfu16(float f) {   // RNE, finite inputs
    union { float f; u32 i; } x; x.f = f;
    return (u16)((x.i + 0x7fffu + ((x.i >> 16) & 1u)) >> 16);
}
__device__ __forceinline__ h2v u32_to_h2v(u32 u) {
    union { u32 i; h2v h; } x; x.i = u; return x.h;
}
__device__ __forceinline__ u16 f16bits(float f) {
    union { __half h; u16 u; } x; x.h = __float2half(f); return x.u;
}
__device__ __forceinline__ float h16_to_f(u16 u) {
    union { u16 u; __half h; } x; x.u = u; return __half2float(x.h);
}

// ---- merged prep: EA table | per-q tables | W1 pack | aux-output zeroing ----
__global__ __launch_bounds__(256) void prep(
        const float* __restrict__ qemb, const float* __restrict__ km,
        const float* __restrict__ w1,   const float* __restrict__ b1,
        const float* __restrict__ qaemb,
        const float* __restrict__ ew,   const float* __restrict__ ebias,
        const float* __restrict__ aw,   const float* __restrict__ abias,
        float* __restrict__ Wt, u32* __restrict__ Wh, float* __restrict__ Q1,
        u32* __restrict__ EA, u16* __restrict__ W1s,
        float* __restrict__ out_aux) {
    const int tid = threadIdx.x;
    const int blk = blockIdx.x;

    // every block zeroes its slice of outputs 1..3 (replaces hipMemsetAsync)
    for (size_t i = (size_t)blk * 256 + tid; i < 3ull * BB * SS;
         i += (size_t)PREP_G * 256)
        out_aux[i] = 0.f;

    __shared__ float smem[VD * EA_R];             // 12.8 KB (EA role); WQ uses 256

    if (blk < EA_B) {
        // ---------------- EA role: {-e, a} packed f16 ----------------
        const int r0 = blk * EA_R;
        if (tid < VD) {
            #pragma unroll
            for (int r = 0; r < EA_R; ++r) {
                int row = r0 + r;
                smem[tid * EA_R + r] = (row < NQA) ? qaemb[(size_t)row * VD + tid] : 0.f;
            }
        }
        __syncthreads();
        if (tid >= VD) return;

        float accE[EA_R], accA[EA_R];
        #pragma unroll
        for (int r = 0; r < EA_R; ++r) { accE[r] = 0.f; accA[r] = 0.f; }
        for (int k = 0; k < VD; ++k) {
            float we = ew[k * VD + tid];
            float wa = aw[k * VD + tid];
            #pragma unroll
            for (int r = 0; r < EA_R; ++r) {
                float qv = smem[k * EA_R + r];
                accE[r] = fmaf(qv, we, accE[r]);
                accA[r] = fmaf(qv, wa, accA[r]);
            }
        }
        float be = ebias[tid], ba = abias[tid];
        #pragma unroll
        for (int r = 0; r < EA_R; ++r) {
            int row = r0 + r;
            if (row < NQA) {
                u16 ne16 = f16bits(-fast_sigmoid(accE[r] + be));   // -e
                u16 a16  = f16bits(fast_tanh(accA[r] + ba));       //  a
                EA[(size_t)row * VD + tid] = (u32)ne16 | ((u32)a16 << 16);
            }
        }
    } else if (blk < EA_B + WQ_B) {
        // ---------------- WQ role (== proven build_wq, 4 q/block) ----------------
        const int lane = tid & 63;
        const int wv   = tid >> 6;
        const int q    = (blk - EA_B) * 4 + wv;
        const bool qok = q < NQ1;
        float* qrow = smem + wv * 64;             // 50 used per wave
        if (qok && lane < KD) qrow[lane] = qemb[q * KD + lane];
        __syncthreads();
        if (!qok) return;

        float s = -1e30f;
        if (lane < MEMN) {
            s = 0.f;
            #pragma unroll
            for (int k = 0; k < KD; ++k) s = fmaf(qrow[k], km[lane * KD + k], s);
        }
        float mx = s;
        #pragma unroll
        for (int off = 32; off >= 1; off >>= 1) mx = fmaxf(mx, __shfl_xor(mx, off, 64));
        float e = (lane < MEMN) ? __expf(s - mx) : 0.f;
        float sum = e;
        #pragma unroll
        for (int off = 32; off >= 1; off >>= 1) sum += __shfl_xor(sum, off, 64);
        float wv_ = (lane < MEMN) ? (e / sum) : 0.f;
        if (lane < MEMN) Wt[q * MEMN + lane] = wv_;

        // f16-pair row: lane i<25 packs (w[2i], w[2i+1]); pairs 25..31 zero
        float plo = __shfl(wv_, 2 * (lane & 31), 64);
        float phi = __shfl(wv_, 2 * (lane & 31) + 1, 64);
        if (lane < 25) {
            Wh[q * WHS + lane] = (u32)f16bits(plo) | ((u32)f16bits(phi) << 16);
        } else if (lane < WHS) {
            Wh[q * WHS + lane] = 0;
        }

        if (lane < FC) {
            float h = b1[lane];
            #pragma unroll
            for (int k = 0; k < KD; ++k)
                h = fmaf(qrow[k], w1[(VD + k) * FC + lane], h);
            Q1[q * FC + lane] = h;
        }
    } else {
        // ---------------- pack role (== proven pack_w1) ----------------
        for (int idx = (blk - EA_B - WQ_B) * 256 + tid; idx < 4 * 7 * 64 * 8;
             idx += PACK_B * 256) {
            int j    = idx & 7;
            int lane = (idx >> 3) & 63;
            int kt   = (idx >> 9) % 7;
            int nt   = idx / 3584;
            int k = kt * 32 + ((lane >> 4) << 3) + j;
            int n = nt * 16 + (lane & 15);
            float v = (k < VD && n < FC) ? w1[k * FC + n] : 0.f;
            W1s[idx] = f_to_bfu16(v);
        }
    }
}

// one recurrence step for 64 dense columns; w row in VGPRs (6x dwordx4 + 1)
__device__ __forceinline__ void state_step_v(const u4v (&w)[6], u32 w6, u32 ea,
                                             h2v (&mv)[25], float& rdA, float& rdB) {
    // ea = {-e (lo f16), a (hi f16)}; broadcast halves via v_perm
    h2v nev2 = u32_to_h2v(__builtin_amdgcn_perm(ea, ea, 0x01000100u));
    h2v av2  = u32_to_h2v(__builtin_amdgcn_perm(ea, ea, 0x03020302u));
    rdA = 0.f; rdB = 0.f;
    #pragma unroll
    for (int i = 0; i < 25; i += 2) {        // 13 iters (i=24 single)
        u32 wu0 = (i < 24) ? w[i >> 2][i & 3] : w6;     // compile-time select
        h2v w0 = u32_to_h2v(wu0);
#if __has_builtin(__builtin_amdgcn_fdot2)
        rdA = __builtin_amdgcn_fdot2(w0, mv[i], rdA, false);
#else
        rdA = fmaf((float)w0.x, (float)mv[i].x,
              fmaf((float)w0.y, (float)mv[i].y, rdA));
#endif
        mv[i] = __builtin_elementwise_fma(
            w0, __builtin_elementwise_fma(nev2, mv[i], av2), mv[i]);
        if (i + 1 < 25) {
            h2v w1p = u32_to_h2v(w[(i + 1) >> 2][(i + 1) & 3]);
#if __has_builtin(__builtin_amdgcn_fdot2)
            rdB = __builtin_amdgcn_fdot2(w1p, mv[i + 1], rdB, false);
#else
            rdB = fmaf((float)w1p.x, (float)mv[i + 1].x,
                  fmaf((float)w1p.y, (float)mv[i + 1].y, rdB));
#endif
            mv[i + 1] = __builtin_elementwise_fma(
                w1p, __builtin_elementwise_fma(nev2, mv[i + 1], av2), mv[i + 1]);
        }
    }
}

// ---- recurrence: BB*2 two-wave blocks, NO scalar-memory ops in hot loop ----
//  blk even -> roles {0,1}; blk odd -> roles {2, tail}; b = blk>>1.
//  qd/qad staged into LDS once per block; per-step uniform ds_read (DS is
//  in-order -> precise lgkm waits), depth-3. Wh row via VMEM uniform-address
//  broadcast loads (vmcnt in-order -> real prefetch), single buffer refilled
//  after consumption. asm "+v" pins q in VGPR to block SMEM re-scalarization.
__global__ __launch_bounds__(128) void dkvmn_state(
        const int* __restrict__ qd, const int* __restrict__ qad,
        const u32* __restrict__ Wh, const u32* __restrict__ EA,
        const float* __restrict__ ivm, u16* __restrict__ READ) {
    const int tid  = threadIdx.x;          // 0..127
    const int lane = tid & 63;
    const int wid  = tid >> 6;             // 0,1
    const int blk  = blockIdx.x;
    const int b    = blk >> 1;
    const int role = (blk & 1) * 2 + wid;  // 0..3
    const int base = b * SS;

    __shared__ int qs[SS], qas[SS];        // 1.6 KB
    for (int i = tid; i < SS; i += 128) {
        qs[i]  = qd[base + i];
        qas[i] = qad[base + i];
    }
    __syncthreads();

    if (role < 3) {
        // ---------------- heavy wave: 64 unique columns ----------------
        const int v = role * 64 + lane;    // < 192, every lane unique

        h2v mv[25];                        // pair i = slots (2i, 2i+1)
        #pragma unroll
        for (int i = 0; i < 25; ++i) {
            mv[i].x = (_Float16)ivm[(2 * i) * VD + v];
            mv[i].y = (_Float16)ivm[(2 * i + 1) * VD + v];
        }

        // q pipeline (VGPR-opaque): qw = q(t+1) for refill, qw2 = q(t+2)
        int q0  = qs[0];  asm volatile("" : "+v"(q0));
        int qw  = qs[1];  asm volatile("" : "+v"(qw));
        int qw2 = qs[2];  asm volatile("" : "+v"(qw2));
        int qa2 = qas[2];                  // qa(t+2) for ea issue
        u32 ea_c = EA[(size_t)qas[0] * VD + v];
        u32 ea_n = EA[(size_t)qas[1] * VD + v];

        // w buffer: pairs 0..24 of row q(t), via uniform-address VMEM loads
        u4v wA[6]; u32 wA6;
        {
            const u32* rp = Wh + (size_t)q0 * WHS;
            #pragma unroll
            for (int j = 0; j < 6; ++j) wA[j] = *(const u4v*)(rp + j * 4);
            wA6 = rp[24];
        }

        for (int t = 0; t < SS; ++t) {
            // depth-3 q/qa reads (in-order DS, used next step)
            int t3 = t + 3; t3 = (t3 < SS) ? t3 : (SS - 1);
            int qnew  = qs[t3];  asm volatile("" : "+v"(qnew));
            int qanew = qas[t3];

            // ea for t+2 (VMEM, depth-2)
            u32 ea_f = EA[(size_t)qa2 * VD + v];

            // consume w(t), ea(t)
            float rdA, rdB;
            state_step_v(wA, wA6, ea_c, mv, rdA, rdB);
            READ[(size_t)(base + t) * VD + v] = f_to_bfu16(rdA + rdB);

            // refill w <- row q(t+1); consumed next step (~1 SIMD rotation)
            {
                const u32* rp = Wh + (size_t)qw * WHS;
                #pragma unroll
                for (int j = 0; j < 6; ++j) wA[j] = *(const u4v*)(rp + j * 4);
                wA6 = rp[24];
            }

            // rotate pipelines
            qw = qw2; qw2 = qnew; qa2 = qanew;
            ea_c = ea_n; ea_n = ea_f;
        }
    } else {
        // ---------------- tail wave: v = 192..199, 8 slot-groups ----------------
        const int v8  = lane & 7;
        const int grp = lane >> 3;         // owns pairs grp*4 .. grp*4+3
        const int v   = 192 + v8;

        h2v mv4[4];
        #pragma unroll
        for (int j = 0; j < 4; ++j) {
            int p = grp * 4 + j;
            if (p < 25) {
                mv4[j].x = (_Float16)ivm[(2 * p) * VD + v];
                mv4[j].y = (_Float16)ivm[(2 * p + 1) * VD + v];
            } else {                       // padded pairs: w=0 keeps them 0
                mv4[j].x = (_Float16)0.f;
                mv4[j].y = (_Float16)0.f;
            }
        }

        int q0 = qs[0], q1 = qs[1];
        u32 ea_c = EA[(size_t)qas[0] * VD + v];
        u32 ea_n = EA[(size_t)qas[1] * VD + v];
        u4v wq_c = *(const u4v*)(Wh + (size_t)q0 * WHS + grp * 4);
        u4v wq_n = *(const u4v*)(Wh + (size_t)q1 * WHS + grp * 4);

        for (int t = 0; t < SS; ++t) {
            int tn = t + 2; tn = (tn < SS) ? tn : (SS - 1);
            int q_nn  = qs[tn];
            int qa_nn = qas[tn];
            u32 ea_nn = EA[(size_t)qa_nn * VD + v];
            u4v wq_nn = *(const u4v*)(Wh + (size_t)q_nn * WHS + grp * 4);

            h2v nev2 = u32_to_h2v(__builtin_amdgcn_perm(ea_c, ea_c, 0x01000100u));
            h2v av2  = u32_to_h2v(__builtin_amdgcn_perm(ea_c, ea_c, 0x03020302u));

            float rd = 0.f;
            #pragma unroll
            for (int j = 0; j < 4; ++j) {
                h2v w2 = u32_to_h2v(wq_c[j]);
#if __has_builtin(__builtin_amdgcn_fdot2)
                rd = __builtin_amdgcn_fdot2(w2, mv4[j], rd, false);
#else
                rd = fmaf((float)w2.x, (float)mv4[j].x,
                     fmaf((float)w2.y, (float)mv4[j].y, rd));
#endif
                mv4[j] = __builtin_elementwise_fma(
                    w2, __builtin_elementwise_fma(nev2, mv4[j], av2), mv4[j]);
            }
            // reduce over the 8 slot-groups (lane stride 8)
            rd += __shfl_xor(rd, 8, 64);
            rd += __shfl_xor(rd, 16, 64);
            rd += __shfl_xor(rd, 32, 64);
            if (grp == 0)
                READ[(size_t)(base + t) * VD + v] = f_to_bfu16(rd);

            ea_c = ea_n; ea_n = ea_nn;
            wq_c = wq_n; wq_n = wq_nn;
        }
    }
}

// ---- prediction MLP via MFMA: per wave one 16-row strip, K=224, N=64 ----
__global__ __launch_bounds__(256) void mlp_pred(
        const u16* __restrict__ RD, const int* __restrict__ qd,
        const float* __restrict__ Q1tab, const u16* __restrict__ W1s,
        const float* __restrict__ w2, const float* __restrict__ b2,
        float* __restrict__ out) {
    const int tid  = threadIdx.x;
    const int lane = tid & 63;
    const int wv   = tid >> 6;
    const int strip = blockIdx.x * 4 + wv;
    const int row0  = strip * 16;

    const int mrow = lane & 15;        // A row within strip / C-D col (feature)
    const int quad = lane >> 4;

    s8v a[7];
    {
        const u16* arow = RD + (size_t)(row0 + mrow) * VD + quad * 8;
        #pragma unroll
        for (int kt = 0; kt < 7; ++kt)
            a[kt] = *(const s8v*)(arow + kt * 32);   // k>=200 garbage * B=0
    }

    const float b2f = b2[0];
    float pf[4] = {0.f, 0.f, 0.f, 0.f};

    #pragma unroll
    for (int nt = 0; nt < 4; ++nt) {
        s8v bfr[7];
        #pragma unroll
        for (int kt = 0; kt < 7; ++kt)
            bfr[kt] = *(const s8v*)(W1s + (((nt * 7 + kt) * 64) + lane) * 8);

        f4v acc = {0.f, 0.f, 0.f, 0.f};
        #pragma unroll
        for (int kt = 0; kt < 7; ++kt)
            acc = __builtin_amdgcn_mfma_f32_16x16x32_bf16(a[kt], bfr[kt], acc, 0, 0, 0);

        const int f = nt * 16 + mrow;                  // output feature col
        const float w2f = (f < FC) ? w2[f] : 0.f;
        #pragma unroll
        for (int r = 0; r < 4; ++r) {
            int row = row0 + quad * 4 + r;
            float h = acc[r] + Q1tab[qd[row] * FC + f];
            pf[r] = fmaf(fast_tanh(h), w2f, pf[r]);
        }
    }

    #pragma unroll
    for (int r = 0; r < 4; ++r) {
        float s = pf[r];
        s += __shfl_xor(s, 1, 64);
        s += __shfl_xor(s, 2, 64);
        s += __shfl_xor(s, 4, 64);
        s += __shfl_xor(s, 8, 64);
        if (mrow == 0)
            out[row0 + quad * 4 + r] = fast_sigmoid(s + b2f);
    }
}

// ---- fallback (barrier version, f32) if workspace too small ----
__global__ void dkvmn_main(const int* __restrict__ qd, const int* __restrict__ qad,
                           const float* __restrict__ Wtab, const float* __restrict__ Q1tab,
                           const u32* __restrict__ EA,
                           const float* __restrict__ ivm,
                           const float* __restrict__ w1,
                           const float* __restrict__ w2,
                           const float* __restrict__ b2,
                           float* __restrict__ out) {
    const int tid  = threadIdx.x;
    const int b    = blockIdx.x;
    const int v    = tid;
    const int lane = tid & 63;
    const int wv   = tid >> 6;

    __shared__ alignas(16) float read_lds[4 * 52];
    __shared__ alignas(16) float part_lds[4 * 52];

    float mv[MEMN];
    if (v < VD) {
        #pragma unroll
        for (int m = 0; m < MEMN; ++m) mv[m] = ivm[m * VD + v];
    }
    float w1r[50];
    if (lane < FC) {
        #pragma unroll
        for (int i = 0; i < 50; ++i) w1r[i] = w1[(wv * 50 + i) * FC + lane];
    } else {
        #pragma unroll
        for (int i = 0; i < 50; ++i) w1r[i] = 0.f;
    }
    const float w2f = (tid < FC) ? w2[tid] : 0.f;
    const float b2f = b2[0];

    const int* qrow_i  = qd  + b * SS;
    const int* qarow_i = qad + b * SS;
    const int jchunk = v / 50;
    const int wslot  = jchunk * 52 + (v - jchunk * 50);

    for (int t = 0; t < SS; ++t) {
        const int q  = __builtin_amdgcn_readfirstlane(qrow_i[t]);
        const int qa = __builtin_amdgcn_readfirstlane(qarow_i[t]);
        const float* wrow = Wtab + q * MEMN;

        u32 ea = 0;
        if (v < VD) ea = EA[(size_t)qa * VD + v];
        float ne = h16_to_f((u16)(ea & 0xffffu));   // -e
        float av = h16_to_f((u16)(ea >> 16));       //  a

        if (v < VD) {
            float rd0 = 0.f, rd1 = 0.f;
            #pragma unroll
            for (int m = 0; m < MEMN; m += 2) {
                float wm0 = wrow[m], wm1 = wrow[m + 1];
                rd0 = fmaf(wm0, mv[m], rd0);
                mv[m] = fmaf(wm0, fmaf(ne, mv[m], av), mv[m]);
                rd1 = fmaf(wm1, mv[m + 1], rd1);
                mv[m + 1] = fmaf(wm1, fmaf(ne, mv[m + 1], av), mv[m + 1]);
            }
            read_lds[wslot] = rd0 + rd1;
        }
        __syncthreads();

        float part = 0.f;
        {
            const float* rlc = read_lds + wv * 52;
            #pragma unroll
            for (int i = 0; i < 48; i += 4) {
                float4 x = *(const float4*)(rlc + i);
                part = fmaf(x.x, w1r[i],     part);
                part = fmaf(x.y, w1r[i + 1], part);
                part = fmaf(x.z, w1r[i + 2], part);
                part = fmaf(x.w, w1r[i + 3], part);
            }
            part = fmaf(rlc[48], w1r[48], part);
            part = fmaf(rlc[49], w1r[49], part);
        }
        if (lane < FC) part_lds[wv * 52 + lane] = part;
        __syncthreads();

        if (wv == 0) {
            float pf = 0.f;
            if (lane < FC) {
                float h = part_lds[lane] + part_lds[52 + lane] +
                          part_lds[104 + lane] + part_lds[156 + lane] +
                          Q1tab[q * FC + lane];
                pf = fast_tanh(h) * w2f;
            }
            #pragma unroll
            for (int off = 32; off >= 1; off >>= 1) pf += __shfl_xor(pf, off, 64);
            if (lane == 0) out[b * SS + t] = fast_sigmoid(pf + b2f);
        }
    }
}

extern "C" void kernel_launch(void* const* d_in, const int* in_sizes, int n_in,
                              void* d_out, int out_size, void* d_ws, size_t ws_size,
                              hipStream_t stream) {
    const int* qd  = (const int*)d_in[0];
    const int* qad = (const int*)d_in[1];
    const float* qemb  = (const float*)d_in[2];
    const float* qaemb = (const float*)d_in[3];
    const float* km    = (const float*)d_in[4];
    const float* ivm   = (const float*)d_in[5];
    const float* ew    = (const float*)d_in[6];
    const float* eb    = (const float*)d_in[7];
    const float* aw    = (const float*)d_in[8];
    const float* ab    = (const float*)d_in[9];
    const float* w1    = (const float*)d_in[10];
    const float* b1    = (const float*)d_in[11];
    const float* w2    = (const float*)d_in[12];
    const float* b2    = (const float*)d_in[13];
    float* out = (float*)d_out;
    (void)in_sizes; (void)n_in; (void)out_size;

    char* ws = (char*)d_ws;
    float* Wt  = (float*)(ws);                       // 1,000,200 -> pad 1,000,448
    float* Q1  = (float*)(ws + 1000448);             // 1,000,200 -> pad 1,000,448
    u32*   EA  = (u32*)  (ws + 2000896);             // 8,000,800 -> pad 8,001,024
    u16*   W1s = (u16*)  (ws + 10001920);            // 28,672    -> pad 32,768
    u32*   Wh  = (u32*)  (ws + 10034688);            // 640,128   -> pad 640,512
    u16*   RD  = (u16*)  (ws + 10675200);            // 163,840,000
    const size_t need = 10675200ull + 163840000ull + 512ull;

    // prep: EA + Wt/Wh/Q1 + W1s + zero outputs 1..3 (one dispatch)
    prep<<<PREP_G, 256, 0, stream>>>(qemb, km, w1, b1, qaemb, ew, eb, aw, ab,
                                     Wt, Wh, Q1, EA, W1s, out + (size_t)BB * SS);

    if (ws_size >= need) {
        dkvmn_state<<<BB * 2, 128, 0, stream>>>(qd, qad, Wh, EA, ivm, RD);
        mlp_pred<<<(BB * SS) / 64, 256, 0, stream>>>(RD, qd, Q1, W1s, w2, b2, out);
    } else {
        dkvmn_main<<<BB, 256, 0, stream>>>(qd, qad, Wt, Q1, EA, ivm, w1, w2, b2, out);
    }
}

// Round 4
// 505.341 us; speedup vs baseline: 1.0039x; 1.0039x over previous
//
#include <hip/hip_runtime.h>
#include <hip/hip_fp16.h>

// DKVMN forward, v21 = v19/v20 hybrid: zero scalar-mem hot loop + correctly
//  phased VMEM w-row pipeline.
//  R3 post-mortem: v20's VMEM broadcast regressed (302->378) because the
//  w refill was issued AFTER the consume -> in-order vmcnt exposed a full
//  ~250cyc L2 round trip per wave-step. Mechanism not refuted; phasing was.
//  v21 heavy wave: two reg buffers wA/wB; at step t ISSUE row q(t+1) into
//  the idle buffer FIRST (7 uniform-address VMEM loads), THEN consume the
//  current buffer. Consume's vmcnt wait targets a load issued a full
//  step-wall (~2000cyc) earlier -> covered 10x. Register deps give the
//  compiler precise automatic vmcnt placement. qd/qad stay in LDS (staged
//  once, in-order DS); ea stays depth-2 VMEM. No SMEM in the hot loop ->
//  the per-CU scalar miss path (the suspected serializer pinning v17-v19
//  at 300-326us) is bypassed entirely.
//  Math bit-identical to v18/v19/v20 (same fdot2+hfma2 order, same w bits).
//  k1 prep : EA {-e,a} f16 | Wt/Wh/Q1 | W1s pack | zero outputs 1..3.
//  k3 mlp_pred : MFMA 16x16x32 bf16 GEMM [B*S,224]@[224,64] + fused epilogue.
// Workspace: Wt 1MB | Q1 1MB | EA 8MB | W1s 32KB | Wh 0.64MB | RD 164MB.

#define NQ1   5001
#define NQA   10001
#define MEMN  50
#define KD    50
#define VD    200
#define FC    50
#define BB    2048
#define SS    200
#define EA_R  16
#define WHS   32       // Wh row stride in u32 (25 pairs + 7 zero pad, 128B)

#define EA_B   626     // ceil(10001/16)
#define WQ_B   1251    // ceil(5001/4)
#define PACK_B 8
#define PREP_G (EA_B + WQ_B + PACK_B)   // 1885 blocks

typedef unsigned int   u32;
typedef unsigned short u16;
typedef short    s8v __attribute__((ext_vector_type(8)));   // 8 bf16 (4 VGPRs)
typedef float    f4v __attribute__((ext_vector_type(4)));   // MFMA C/D
typedef _Float16 h2v __attribute__((ext_vector_type(2)));   // packed f16 pair
typedef u32      u4v __attribute__((ext_vector_type(4)));   // dwordx4

__device__ __forceinline__ float fast_sigmoid(float x) { return 1.f / (1.f + __expf(-x)); }
__device__ __forceinline__ float fast_tanh(float x) {
    float e2 = __expf(2.f * x);           // inf-safe
    return 1.f - 2.f / (e2 + 1.f);
}
__device__ __forceinline__ float bfu16_to_f(u16 u) {
    union { float f; u32 i; } x; x.i = ((u32)u) << 16; return x.f;
}
__device__ __forceinline__ u16 f_to_bfu16(float f) {   // RNE, finite inputs
    union { float f; u32 i; } x; x.f = f;
    return (u16)((x.i + 0x7fffu + ((x.i >> 16) & 1u)) >> 16);
}
__device__ __forceinline__ h2v u32_to_h2v(u32 u) {
    union { u32 i; h2v h; } x; x.i = u; return x.h;
}
__device__ __forceinline__ u16 f16bits(float f) {
    union { __half h; u16 u; } x; x.h = __float2half(f); return x.u;
}
__device__ __forceinline__ float h16_to_f(u16 u) {
    union { u16 u; __half h; } x; x.u = u; return __half2float(x.h);
}

// ---- merged prep: EA table | per-q tables | W1 pack | aux-output zeroing ----
__global__ __launch_bounds__(256) void prep(
        const float* __restrict__ qemb, const float* __restrict__ km,
        const float* __restrict__ w1,   const float* __restrict__ b1,
        const float* __restrict__ qaemb,
        const float* __restrict__ ew,   const float* __restrict__ ebias,
        const float* __restrict__ aw,   const float* __restrict__ abias,
        float* __restrict__ Wt, u32* __restrict__ Wh, float* __restrict__ Q1,
        u32* __restrict__ EA, u16* __restrict__ W1s,
        float* __restrict__ out_aux) {
    const int tid = threadIdx.x;
    const int blk = blockIdx.x;

    // every block zeroes its slice of outputs 1..3 (replaces hipMemsetAsync)
    for (size_t i = (size_t)blk * 256 + tid; i < 3ull * BB * SS;
         i += (size_t)PREP_G * 256)
        out_aux[i] = 0.f;

    __shared__ float smem[VD * EA_R];             // 12.8 KB (EA role); WQ uses 256

    if (blk < EA_B) {
        // ---------------- EA role: {-e, a} packed f16 ----------------
        const int r0 = blk * EA_R;
        if (tid < VD) {
            #pragma unroll
            for (int r = 0; r < EA_R; ++r) {
                int row = r0 + r;
                smem[tid * EA_R + r] = (row < NQA) ? qaemb[(size_t)row * VD + tid] : 0.f;
            }
        }
        __syncthreads();
        if (tid >= VD) return;

        float accE[EA_R], accA[EA_R];
        #pragma unroll
        for (int r = 0; r < EA_R; ++r) { accE[r] = 0.f; accA[r] = 0.f; }
        for (int k = 0; k < VD; ++k) {
            float we = ew[k * VD + tid];
            float wa = aw[k * VD + tid];
            #pragma unroll
            for (int r = 0; r < EA_R; ++r) {
                float qv = smem[k * EA_R + r];
                accE[r] = fmaf(qv, we, accE[r]);
                accA[r] = fmaf(qv, wa, accA[r]);
            }
        }
        float be = ebias[tid], ba = abias[tid];
        #pragma unroll
        for (int r = 0; r < EA_R; ++r) {
            int row = r0 + r;
            if (row < NQA) {
                u16 ne16 = f16bits(-fast_sigmoid(accE[r] + be));   // -e
                u16 a16  = f16bits(fast_tanh(accA[r] + ba));       //  a
                EA[(size_t)row * VD + tid] = (u32)ne16 | ((u32)a16 << 16);
            }
        }
    } else if (blk < EA_B + WQ_B) {
        // ---------------- WQ role (== proven build_wq, 4 q/block) ----------------
        const int lane = tid & 63;
        const int wv   = tid >> 6;
        const int q    = (blk - EA_B) * 4 + wv;
        const bool qok = q < NQ1;
        float* qrow = smem + wv * 64;             // 50 used per wave
        if (qok && lane < KD) qrow[lane] = qemb[q * KD + lane];
        __syncthreads();
        if (!qok) return;

        float s = -1e30f;
        if (lane < MEMN) {
            s = 0.f;
            #pragma unroll
            for (int k = 0; k < KD; ++k) s = fmaf(qrow[k], km[lane * KD + k], s);
        }
        float mx = s;
        #pragma unroll
        for (int off = 32; off >= 1; off >>= 1) mx = fmaxf(mx, __shfl_xor(mx, off, 64));
        float e = (lane < MEMN) ? __expf(s - mx) : 0.f;
        float sum = e;
        #pragma unroll
        for (int off = 32; off >= 1; off >>= 1) sum += __shfl_xor(sum, off, 64);
        float wv_ = (lane < MEMN) ? (e / sum) : 0.f;
        if (lane < MEMN) Wt[q * MEMN + lane] = wv_;

        // f16-pair row: lane i<25 packs (w[2i], w[2i+1]); pairs 25..31 zero
        float plo = __shfl(wv_, 2 * (lane & 31), 64);
        float phi = __shfl(wv_, 2 * (lane & 31) + 1, 64);
        if (lane < 25) {
            Wh[q * WHS + lane] = (u32)f16bits(plo) | ((u32)f16bits(phi) << 16);
        } else if (lane < WHS) {
            Wh[q * WHS + lane] = 0;
        }

        if (lane < FC) {
            float h = b1[lane];
            #pragma unroll
            for (int k = 0; k < KD; ++k)
                h = fmaf(qrow[k], w1[(VD + k) * FC + lane], h);
            Q1[q * FC + lane] = h;
        }
    } else {
        // ---------------- pack role (== proven pack_w1) ----------------
        for (int idx = (blk - EA_B - WQ_B) * 256 + tid; idx < 4 * 7 * 64 * 8;
             idx += PACK_B * 256) {
            int j    = idx & 7;
            int lane = (idx >> 3) & 63;
            int kt   = (idx >> 9) % 7;
            int nt   = idx / 3584;
            int k = kt * 32 + ((lane >> 4) << 3) + j;
            int n = nt * 16 + (lane & 15);
            float v = (k < VD && n < FC) ? w1[k * FC + n] : 0.f;
            W1s[idx] = f_to_bfu16(v);
        }
    }
}

// one recurrence step for 64 dense columns; w row in VGPRs (6x dwordx4 + 1)
__device__ __forceinline__ void state_step_v(const u4v (&w)[6], u32 w6, u32 ea,
                                             h2v (&mv)[25], float& rdA, float& rdB) {
    // ea = {-e (lo f16), a (hi f16)}; broadcast halves via v_perm
    h2v nev2 = u32_to_h2v(__builtin_amdgcn_perm(ea, ea, 0x01000100u));
    h2v av2  = u32_to_h2v(__builtin_amdgcn_perm(ea, ea, 0x03020302u));
    rdA = 0.f; rdB = 0.f;
    #pragma unroll
    for (int i = 0; i < 25; i += 2) {        // 13 iters (i=24 single)
        u32 wu0 = (i < 24) ? w[i >> 2][i & 3] : w6;     // compile-time select
        h2v w0 = u32_to_h2v(wu0);
#if __has_builtin(__builtin_amdgcn_fdot2)
        rdA = __builtin_amdgcn_fdot2(w0, mv[i], rdA, false);
#else
        rdA = fmaf((float)w0.x, (float)mv[i].x,
              fmaf((float)w0.y, (float)mv[i].y, rdA));
#endif
        mv[i] = __builtin_elementwise_fma(
            w0, __builtin_elementwise_fma(nev2, mv[i], av2), mv[i]);
        if (i + 1 < 25) {
            h2v w1p = u32_to_h2v(w[(i + 1) >> 2][(i + 1) & 3]);
#if __has_builtin(__builtin_amdgcn_fdot2)
            rdB = __builtin_amdgcn_fdot2(w1p, mv[i + 1], rdB, false);
#else
            rdB = fmaf((float)w1p.x, (float)mv[i + 1].x,
                  fmaf((float)w1p.y, (float)mv[i + 1].y, rdB));
#endif
            mv[i + 1] = __builtin_elementwise_fma(
                w1p, __builtin_elementwise_fma(nev2, mv[i + 1], av2), mv[i + 1]);
        }
    }
}

// ---- recurrence: BB*2 two-wave blocks, NO scalar-memory ops in hot loop ----
//  blk even -> roles {0,1}; blk odd -> roles {2, tail}; b = blk>>1.
//  qd/qad staged once into LDS (in-order DS, depth-3 reads).
//  Heavy wave w row: VMEM uniform-address broadcast loads, depth-1 ping-pong
//  with ISSUE-BEFORE-CONSUME phasing -> consume's vmcnt wait targets a load
//  issued one full step-wall earlier (covered). ea: depth-2 VMEM.
__global__ __launch_bounds__(128) void dkvmn_state(
        const int* __restrict__ qd, const int* __restrict__ qad,
        const u32* __restrict__ Wh, const u32* __restrict__ EA,
        const float* __restrict__ ivm, u16* __restrict__ READ) {
    const int tid  = threadIdx.x;          // 0..127
    const int lane = tid & 63;
    const int wid  = tid >> 6;             // 0,1
    const int blk  = blockIdx.x;
    const int b    = blk >> 1;
    const int role = (blk & 1) * 2 + wid;  // 0..3
    const int base = b * SS;

    __shared__ int qs[SS], qas[SS];        // 1.6 KB
    for (int i = tid; i < SS; i += 128) {
        qs[i]  = qd[base + i];
        qas[i] = qad[base + i];
    }
    __syncthreads();

    if (role < 3) {
        // ---------------- heavy wave: 64 unique columns ----------------
        const int v = role * 64 + lane;    // < 192, every lane unique

        h2v mv[25];                        // pair i = slots (2i, 2i+1)
        #pragma unroll
        for (int i = 0; i < 25; ++i) {
            mv[i].x = (_Float16)ivm[(2 * i) * VD + v];
            mv[i].y = (_Float16)ivm[(2 * i + 1) * VD + v];
        }

        // q pipeline (VGPR-pinned so addressing stays VMEM, never SMEM)
        int q0  = qs[0];  asm volatile("" : "+v"(q0));
        int qn1 = qs[1];  asm volatile("" : "+v"(qn1));   // q(t+1)
        int qn2 = qs[2];  asm volatile("" : "+v"(qn2));   // q(t+2)
        int qan2 = qas[2];                 // qa(t+2)
        int qan3 = qas[3];                 // qa(t+3)
        u32 ea_c = EA[(size_t)qas[0] * VD + v];
        u32 ea_n = EA[(size_t)qas[1] * VD + v];

        u4v wA[6]; u32 wA6;                // w ping-pong buffers
        u4v wB[6]; u32 wB6;
        {
            const u32* rp = Wh + (size_t)q0 * WHS;
            #pragma unroll
            for (int j = 0; j < 6; ++j) wA[j] = *(const u4v*)(rp + j * 4);
            wA6 = rp[24];
        }

        for (int t = 0; t < SS; t += 2) {
            // ===== step t (even): ISSUE wB <- row q(t+1), then consume wA ====
            {
                const u32* rp = Wh + (size_t)qn1 * WHS;
                #pragma unroll
                for (int j = 0; j < 6; ++j) wB[j] = *(const u4v*)(rp + j * 4);
                wB6 = rp[24];

                u32 ea_f = EA[(size_t)qan2 * VD + v];        // ea(t+2)
                int t3 = t + 3; t3 = (t3 < SS) ? t3 : (SS - 1);
                int qnew  = qs[t3];  asm volatile("" : "+v"(qnew));
                int qanew = qas[t3];

                float rdA, rdB;
                state_step_v(wA, wA6, ea_c, mv, rdA, rdB);
                READ[(size_t)(base + t) * VD + v] = f_to_bfu16(rdA + rdB);

                qn1 = qn2; qn2 = qnew; qan2 = qan3; qan3 = qanew;
                ea_c = ea_n; ea_n = ea_f;
            }
            // ===== step t+1 (odd): ISSUE wA <- row q(t+2), then consume wB ===
            {
                const u32* rp = Wh + (size_t)qn1 * WHS;
                #pragma unroll
                for (int j = 0; j < 6; ++j) wA[j] = *(const u4v*)(rp + j * 4);
                wA6 = rp[24];

                u32 ea_f = EA[(size_t)qan2 * VD + v];        // ea(t+3)
                int t4 = t + 4; t4 = (t4 < SS) ? t4 : (SS - 1);
                int qnew  = qs[t4];  asm volatile("" : "+v"(qnew));
                int qanew = qas[t4];

                float rdA, rdB;
                state_step_v(wB, wB6, ea_c, mv, rdA, rdB);
                READ[(size_t)(base + t + 1) * VD + v] = f_to_bfu16(rdA + rdB);

                qn1 = qn2; qn2 = qnew; qan2 = qan3; qan3 = qanew;
                ea_c = ea_n; ea_n = ea_f;
            }
        }
    } else {
        // ---------------- tail wave: v = 192..199, 8 slot-groups ----------------
        const int v8  = lane & 7;
        const int grp = lane >> 3;         // owns pairs grp*4 .. grp*4+3
        const int v   = 192 + v8;

        h2v mv4[4];
        #pragma unroll
        for (int j = 0; j < 4; ++j) {
            int p = grp * 4 + j;
            if (p < 25) {
                mv4[j].x = (_Float16)ivm[(2 * p) * VD + v];
                mv4[j].y = (_Float16)ivm[(2 * p + 1) * VD + v];
            } else {                       // padded pairs: w=0 keeps them 0
                mv4[j].x = (_Float16)0.f;
                mv4[j].y = (_Float16)0.f;
            }
        }

        int q0 = qs[0], q1 = qs[1];
        u32 ea_c = EA[(size_t)qas[0] * VD + v];
        u32 ea_n = EA[(size_t)qas[1] * VD + v];
        u4v wq_c = *(const u4v*)(Wh + (size_t)q0 * WHS + grp * 4);
        u4v wq_n = *(const u4v*)(Wh + (size_t)q1 * WHS + grp * 4);

        for (int t = 0; t < SS; ++t) {
            int tn = t + 2; tn = (tn < SS) ? tn : (SS - 1);
            int q_nn  = qs[tn];
            int qa_nn = qas[tn];
            u32 ea_nn = EA[(size_t)qa_nn * VD + v];
            u4v wq_nn = *(const u4v*)(Wh + (size_t)q_nn * WHS + grp * 4);

            h2v nev2 = u32_to_h2v(__builtin_amdgcn_perm(ea_c, ea_c, 0x01000100u));
            h2v av2  = u32_to_h2v(__builtin_amdgcn_perm(ea_c, ea_c, 0x03020302u));

            float rd = 0.f;
            #pragma unroll
            for (int j = 0; j < 4; ++j) {
                h2v w2 = u32_to_h2v(wq_c[j]);
#if __has_builtin(__builtin_amdgcn_fdot2)
                rd = __builtin_amdgcn_fdot2(w2, mv4[j], rd, false);
#else
                rd = fmaf((float)w2.x, (float)mv4[j].x,
                     fmaf((float)w2.y, (float)mv4[j].y, rd));
#endif
                mv4[j] = __builtin_elementwise_fma(
                    w2, __builtin_elementwise_fma(nev2, mv4[j], av2), mv4[j]);
            }
            // reduce over the 8 slot-groups (lane stride 8)
            rd += __shfl_xor(rd, 8, 64);
            rd += __shfl_xor(rd, 16, 64);
            rd += __shfl_xor(rd, 32, 64);
            if (grp == 0)
                READ[(size_t)(base + t) * VD + v] = f_to_bfu16(rd);

            ea_c = ea_n; ea_n = ea_nn;
            wq_c = wq_n; wq_n = wq_nn;
        }
    }
}

// ---- prediction MLP via MFMA: per wave one 16-row strip, K=224, N=64 ----
__global__ __launch_bounds__(256) void mlp_pred(
        const u16* __restrict__ RD, const int* __restrict__ qd,
        const float* __restrict__ Q1tab, const u16* __restrict__ W1s,
        const float* __restrict__ w2, const float* __restrict__ b2,
        float* __restrict__ out) {
    const int tid  = threadIdx.x;
    const int lane = tid & 63;
    const int wv   = tid >> 6;
    const int strip = blockIdx.x * 4 + wv;
    const int row0  = strip * 16;

    const int mrow = lane & 15;        // A row within strip / C-D col (feature)
    const int quad = lane >> 4;

    s8v a[7];
    {
        const u16* arow = RD + (size_t)(row0 + mrow) * VD + quad * 8;
        #pragma unroll
        for (int kt = 0; kt < 7; ++kt)
            a[kt] = *(const s8v*)(arow + kt * 32);   // k>=200 garbage * B=0
    }

    const float b2f = b2[0];
    float pf[4] = {0.f, 0.f, 0.f, 0.f};

    #pragma unroll
    for (int nt = 0; nt < 4; ++nt) {
        s8v bfr[7];
        #pragma unroll
        for (int kt = 0; kt < 7; ++kt)
            bfr[kt] = *(const s8v*)(W1s + (((nt * 7 + kt) * 64) + lane) * 8);

        f4v acc = {0.f, 0.f, 0.f, 0.f};
        #pragma unroll
        for (int kt = 0; kt < 7; ++kt)
            acc = __builtin_amdgcn_mfma_f32_16x16x32_bf16(a[kt], bfr[kt], acc, 0, 0, 0);

        const int f = nt * 16 + mrow;                  // output feature col
        const float w2f = (f < FC) ? w2[f] : 0.f;
        #pragma unroll
        for (int r = 0; r < 4; ++r) {
            int row = row0 + quad * 4 + r;
            float h = acc[r] + Q1tab[qd[row] * FC + f];
            pf[r] = fmaf(fast_tanh(h), w2f, pf[r]);
        }
    }

    #pragma unroll
    for (int r = 0; r < 4; ++r) {
        float s = pf[r];
        s += __shfl_xor(s, 1, 64);
        s += __shfl_xor(s, 2, 64);
        s += __shfl_xor(s, 4, 64);
        s += __shfl_xor(s, 8, 64);
        if (mrow == 0)
            out[row0 + quad * 4 + r] = fast_sigmoid(s + b2f);
    }
}

// ---- fallback (barrier version, f32) if workspace too small ----
__global__ void dkvmn_main(const int* __restrict__ qd, const int* __restrict__ qad,
                           const float* __restrict__ Wtab, const float* __restrict__ Q1tab,
                           const u32* __restrict__ EA,
                           const float* __restrict__ ivm,
                           const float* __restrict__ w1,
                           const float* __restrict__ w2,
                           const float* __restrict__ b2,
                           float* __restrict__ out) {
    const int tid  = threadIdx.x;
    const int b    = blockIdx.x;
    const int v    = tid;
    const int lane = tid & 63;
    const int wv   = tid >> 6;

    __shared__ alignas(16) float read_lds[4 * 52];
    __shared__ alignas(16) float part_lds[4 * 52];

    float mv[MEMN];
    if (v < VD) {
        #pragma unroll
        for (int m = 0; m < MEMN; ++m) mv[m] = ivm[m * VD + v];
    }
    float w1r[50];
    if (lane < FC) {
        #pragma unroll
        for (int i = 0; i < 50; ++i) w1r[i] = w1[(wv * 50 + i) * FC + lane];
    } else {
        #pragma unroll
        for (int i = 0; i < 50; ++i) w1r[i] = 0.f;
    }
    const float w2f = (tid < FC) ? w2[tid] : 0.f;
    const float b2f = b2[0];

    const int* qrow_i  = qd  + b * SS;
    const int* qarow_i = qad + b * SS;
    const int jchunk = v / 50;
    const int wslot  = jchunk * 52 + (v - jchunk * 50);

    for (int t = 0; t < SS; ++t) {
        const int q  = __builtin_amdgcn_readfirstlane(qrow_i[t]);
        const int qa = __builtin_amdgcn_readfirstlane(qarow_i[t]);
        const float* wrow = Wtab + q * MEMN;

        u32 ea = 0;
        if (v < VD) ea = EA[(size_t)qa * VD + v];
        float ne = h16_to_f((u16)(ea & 0xffffu));   // -e
        float av = h16_to_f((u16)(ea >> 16));       //  a

        if (v < VD) {
            float rd0 = 0.f, rd1 = 0.f;
            #pragma unroll
            for (int m = 0; m < MEMN; m += 2) {
                float wm0 = wrow[m], wm1 = wrow[m + 1];
                rd0 = fmaf(wm0, mv[m], rd0);
                mv[m] = fmaf(wm0, fmaf(ne, mv[m], av), mv[m]);
                rd1 = fmaf(wm1, mv[m + 1], rd1);
                mv[m + 1] = fmaf(wm1, fmaf(ne, mv[m + 1], av), mv[m + 1]);
            }
            read_lds[wslot] = rd0 + rd1;
        }
        __syncthreads();

        float part = 0.f;
        {
            const float* rlc = read_lds + wv * 52;
            #pragma unroll
            for (int i = 0; i < 48; i += 4) {
                float4 x = *(const float4*)(rlc + i);
                part = fmaf(x.x, w1r[i],     part);
                part = fmaf(x.y, w1r[i + 1], part);
                part = fmaf(x.z, w1r[i + 2], part);
                part = fmaf(x.w, w1r[i + 3], part);
            }
            part = fmaf(rlc[48], w1r[48], part);
            part = fmaf(rlc[49], w1r[49], part);
        }
        if (lane < FC) part_lds[wv * 52 + lane] = part;
        __syncthreads();

        if (wv == 0) {
            float pf = 0.f;
            if (lane < FC) {
                float h = part_lds[lane] + part_lds[52 + lane] +
                          part_lds[104 + lane] + part_lds[156 + lane] +
                          Q1tab[q * FC + lane];
                pf = fast_tanh(h) * w2f;
            }
            #pragma unroll
            for (int off = 32; off >= 1; off >>= 1) pf += __shfl_xor(pf, off, 64);
            if (lane == 0) out[b * SS + t] = fast_sigmoid(pf + b2f);
        }
    }
}

extern "C" void kernel_launch(void* const* d_in, const int* in_sizes, int n_in,
                              void* d_out, int out_size, void* d_ws, size_t ws_size,
                              hipStream_t stream) {
    const int* qd  = (const int*)d_in[0];
    const int* qad = (const int*)d_in[1];
    const float* qemb  = (const float*)d_in[2];
    const float* qaemb = (const float*)d_in[3];
    const float* km    = (const float*)d_in[4];
    const float* ivm   = (const float*)d_in[5];
    const float* ew    = (const float*)d_in[6];
    const float* eb    = (const float*)d_in[7];
    const float* aw    = (const float*)d_in[8];
    const float* ab    = (const float*)d_in[9];
    const float* w1    = (const float*)d_in[10];
    const float* b1    = (const float*)d_in[11];
    const float* w2    = (const float*)d_in[12];
    const float* b2    = (const float*)d_in[13];
    float* out = (float*)d_out;
    (void)in_sizes; (void)n_in; (void)out_size;

    char* ws = (char*)d_ws;
    float* Wt  = (float*)(ws);                       // 1,000,200 -> pad 1,000,448
    float* Q1  = (float*)(ws + 1000448);             // 1,000,200 -> pad 1,000,448
    u32*   EA  = (u32*)  (ws + 2000896);             // 8,000,800 -> pad 8,001,024
    u16*   W1s = (u16*)  (ws + 10001920);            // 28,672    -> pad 32,768
    u32*   Wh  = (u32*)  (ws + 10034688);            // 640,128   -> pad 640,512
    u16*   RD  = (u16*)  (ws + 10675200);            // 163,840,000
    const size_t need = 10675200ull + 163840000ull + 512ull;

    // prep: EA + Wt/Wh/Q1 + W1s + zero outputs 1..3 (one dispatch)
    prep<<<PREP_G, 256, 0, stream>>>(qemb, km, w1, b1, qaemb, ew, eb, aw, ab,
                                     Wt, Wh, Q1, EA, W1s, out + (size_t)BB * SS);

    if (ws_size >= need) {
        dkvmn_state<<<BB * 2, 128, 0, stream>>>(qd, qad, Wh, EA, ivm, RD);
        mlp_pred<<<(BB * SS) / 64, 256, 0, stream>>>(RD, qd, Q1, W1s, w2, b2, out);
    } else {
        dkvmn_main<<<BB, 256, 0, stream>>>(qd, qad, Wt, Q1, EA, ivm, w1, w2, b2, out);
    }
}

// Round 5
// 463.267 us; speedup vs baseline: 1.0951x; 1.0908x over previous
//
#include <hip/hip_runtime.h>
#include <hip/hip_fp16.h>

// DKVMN forward, v22 = w delivered via LDS broadcast (the only per-CU
//  broadcast path not yet saturated), ea pipeline restored (v21 had an
//  off-by-one: both unroll halves loaded qas[t+3] -> absmax 0.0039->0.0117).
//  Evidence ledger: SMEM w (v17-v19): 302-326us, invariant ~175cyc/wave-step
//  stall = per-CU scalar miss path saturated (32 waves x 25 dwords random
//  row/step). VMEM-broadcast w (v20 exposed / v21 covered+low-occ): both
//  ~380us regardless of phasing OR occupancy -> per-CU vector front-end
//  (TA) saturated: 7 uniform-address insts/wave-step still process 64 lane
//  addresses each. Both broadcast mechanisms bottleneck at the CU front-end.
//  v22: per block, stage 16 steps of Wh rows (2KB) into double-buffered LDS:
//  4 COALESCED per-lane loads per thread per 16 steps (TA cost ~0.125
//  inst/wave-step), ds_writes after the consume, 1 barrier/group. Per step:
//  7 same-address ds_reads (HW broadcast, conflict-free, in-order, precise
//  lgkm). qd/qad already in LDS; ea depth-2 VMEM per-lane (coalesced).
//  Math bit-identical to v18/v19 (same fdot2+hfma2 order, same w bits).
//  k1 prep : EA {-e,a} f16 | Wt/Wh/Q1 | W1s pack | zero outputs 1..3.
//  k3 mlp_pred : MFMA 16x16x32 bf16 GEMM [B*S,224]@[224,64] + fused epilogue.
// Workspace: Wt 1MB | Q1 1MB | EA 8MB | W1s 32KB | Wh 0.64MB | RD 164MB.

#define NQ1   5001
#define NQA   10001
#define MEMN  50
#define KD    50
#define VD    200
#define FC    50
#define BB    2048
#define SS    200
#define EA_R  16
#define WHS   32       // Wh row stride in u32 (25 pairs + 7 zero pad, 128B)

#define EA_B   626     // ceil(10001/16)
#define WQ_B   1251    // ceil(5001/4)
#define PACK_B 8
#define PREP_G (EA_B + WQ_B + PACK_B)   // 1885 blocks

#define WGRP  16       // steps staged per LDS group
#define NG    13       // ceil(200/16); last group has 8 steps

typedef unsigned int   u32;
typedef unsigned short u16;
typedef short    s8v __attribute__((ext_vector_type(8)));   // 8 bf16 (4 VGPRs)
typedef float    f4v __attribute__((ext_vector_type(4)));   // MFMA C/D
typedef _Float16 h2v __attribute__((ext_vector_type(2)));   // packed f16 pair
typedef u32      u4v __attribute__((ext_vector_type(4)));   // dwordx4

__device__ __forceinline__ float fast_sigmoid(float x) { return 1.f / (1.f + __expf(-x)); }
__device__ __forceinline__ float fast_tanh(float x) {
    float e2 = __expf(2.f * x);           // inf-safe
    return 1.f - 2.f / (e2 + 1.f);
}
__device__ __forceinline__ float bfu16_to_f(u16 u) {
    union { float f; u32 i; } x; x.i = ((u32)u) << 16; return x.f;
}
__device__ __forceinline__ u16 f_to_bfu16(float f) {   // RNE, finite inputs
    union { float f; u32 i; } x; x.f = f;
    return (u16)((x.i + 0x7fffu + ((x.i >> 16) & 1u)) >> 16);
}
__device__ __forceinline__ h2v u32_to_h2v(u32 u) {
    union { u32 i; h2v h; } x; x.i = u; return x.h;
}
__device__ __forceinline__ u16 f16bits(float f) {
    union { __half h; u16 u; } x; x.h = __float2half(f); return x.u;
}
__device__ __forceinline__ float h16_to_f(u16 u) {
    union { u16 u; __half h; } x; x.u = u; return __half2float(x.h);
}

// ---- merged prep: EA table | per-q tables | W1 pack | aux-output zeroing ----
__global__ __launch_bounds__(256) void prep(
        const float* __restrict__ qemb, const float* __restrict__ km,
        const float* __restrict__ w1,   const float* __restrict__ b1,
        const float* __restrict__ qaemb,
        const float* __restrict__ ew,   const float* __restrict__ ebias,
        const float* __restrict__ aw,   const float* __restrict__ abias,
        float* __restrict__ Wt, u32* __restrict__ Wh, float* __restrict__ Q1,
        u32* __restrict__ EA, u16* __restrict__ W1s,
        float* __restrict__ out_aux) {
    const int tid = threadIdx.x;
    const int blk = blockIdx.x;

    // every block zeroes its slice of outputs 1..3 (replaces hipMemsetAsync)
    for (size_t i = (size_t)blk * 256 + tid; i < 3ull * BB * SS;
         i += (size_t)PREP_G * 256)
        out_aux[i] = 0.f;

    __shared__ float smem[VD * EA_R];             // 12.8 KB (EA role); WQ uses 256

    if (blk < EA_B) {
        // ---------------- EA role: {-e, a} packed f16 ----------------
        const int r0 = blk * EA_R;
        if (tid < VD) {
            #pragma unroll
            for (int r = 0; r < EA_R; ++r) {
                int row = r0 + r;
                smem[tid * EA_R + r] = (row < NQA) ? qaemb[(size_t)row * VD + tid] : 0.f;
            }
        }
        __syncthreads();
        if (tid >= VD) return;

        float accE[EA_R], accA[EA_R];
        #pragma unroll
        for (int r = 0; r < EA_R; ++r) { accE[r] = 0.f; accA[r] = 0.f; }
        for (int k = 0; k < VD; ++k) {
            float we = ew[k * VD + tid];
            float wa = aw[k * VD + tid];
            #pragma unroll
            for (int r = 0; r < EA_R; ++r) {
                float qv = smem[k * EA_R + r];
                accE[r] = fmaf(qv, we, accE[r]);
                accA[r] = fmaf(qv, wa, accA[r]);
            }
        }
        float be = ebias[tid], ba = abias[tid];
        #pragma unroll
        for (int r = 0; r < EA_R; ++r) {
            int row = r0 + r;
            if (row < NQA) {
                u16 ne16 = f16bits(-fast_sigmoid(accE[r] + be));   // -e
                u16 a16  = f16bits(fast_tanh(accA[r] + ba));       //  a
                EA[(size_t)row * VD + tid] = (u32)ne16 | ((u32)a16 << 16);
            }
        }
    } else if (blk < EA_B + WQ_B) {
        // ---------------- WQ role (== proven build_wq, 4 q/block) ----------------
        const int lane = tid & 63;
        const int wv   = tid >> 6;
        const int q    = (blk - EA_B) * 4 + wv;
        const bool qok = q < NQ1;
        float* qrow = smem + wv * 64;             // 50 used per wave
        if (qok && lane < KD) qrow[lane] = qemb[q * KD + lane];
        __syncthreads();
        if (!qok) return;

        float s = -1e30f;
        if (lane < MEMN) {
            s = 0.f;
            #pragma unroll
            for (int k = 0; k < KD; ++k) s = fmaf(qrow[k], km[lane * KD + k], s);
        }
        float mx = s;
        #pragma unroll
        for (int off = 32; off >= 1; off >>= 1) mx = fmaxf(mx, __shfl_xor(mx, off, 64));
        float e = (lane < MEMN) ? __expf(s - mx) : 0.f;
        float sum = e;
        #pragma unroll
        for (int off = 32; off >= 1; off >>= 1) sum += __shfl_xor(sum, off, 64);
        float wv_ = (lane < MEMN) ? (e / sum) : 0.f;
        if (lane < MEMN) Wt[q * MEMN + lane] = wv_;

        // f16-pair row: lane i<25 packs (w[2i], w[2i+1]); pairs 25..31 zero
        float plo = __shfl(wv_, 2 * (lane & 31), 64);
        float phi = __shfl(wv_, 2 * (lane & 31) + 1, 64);
        if (lane < 25) {
            Wh[q * WHS + lane] = (u32)f16bits(plo) | ((u32)f16bits(phi) << 16);
        } else if (lane < WHS) {
            Wh[q * WHS + lane] = 0;
        }

        if (lane < FC) {
            float h = b1[lane];
            #pragma unroll
            for (int k = 0; k < KD; ++k)
                h = fmaf(qrow[k], w1[(VD + k) * FC + lane], h);
            Q1[q * FC + lane] = h;
        }
    } else {
        // ---------------- pack role (== proven pack_w1) ----------------
        for (int idx = (blk - EA_B - WQ_B) * 256 + tid; idx < 4 * 7 * 64 * 8;
             idx += PACK_B * 256) {
            int j    = idx & 7;
            int lane = (idx >> 3) & 63;
            int kt   = (idx >> 9) % 7;
            int nt   = idx / 3584;
            int k = kt * 32 + ((lane >> 4) << 3) + j;
            int n = nt * 16 + (lane & 15);
            float v = (k < VD && n < FC) ? w1[k * FC + n] : 0.f;
            W1s[idx] = f_to_bfu16(v);
        }
    }
}

// one recurrence step for 64 dense columns; w row in VGPRs (6x b128 + 1)
__device__ __forceinline__ void state_step_v(const u4v (&w)[6], u32 w6, u32 ea,
                                             h2v (&mv)[25], float& rdA, float& rdB) {
    // ea = {-e (lo f16), a (hi f16)}; broadcast halves via v_perm
    h2v nev2 = u32_to_h2v(__builtin_amdgcn_perm(ea, ea, 0x01000100u));
    h2v av2  = u32_to_h2v(__builtin_amdgcn_perm(ea, ea, 0x03020302u));
    rdA = 0.f; rdB = 0.f;
    #pragma unroll
    for (int i = 0; i < 25; i += 2) {        // 13 iters (i=24 single)
        u32 wu0 = (i < 24) ? w[i >> 2][i & 3] : w6;     // compile-time select
        h2v w0 = u32_to_h2v(wu0);
#if __has_builtin(__builtin_amdgcn_fdot2)
        rdA = __builtin_amdgcn_fdot2(w0, mv[i], rdA, false);
#else
        rdA = fmaf((float)w0.x, (float)mv[i].x,
              fmaf((float)w0.y, (float)mv[i].y, rdA));
#endif
        mv[i] = __builtin_elementwise_fma(
            w0, __builtin_elementwise_fma(nev2, mv[i], av2), mv[i]);
        if (i + 1 < 25) {
            h2v w1p = u32_to_h2v(w[(i + 1) >> 2][(i + 1) & 3]);
#if __has_builtin(__builtin_amdgcn_fdot2)
            rdB = __builtin_amdgcn_fdot2(w1p, mv[i + 1], rdB, false);
#else
            rdB = fmaf((float)w1p.x, (float)mv[i + 1].x,
                  fmaf((float)w1p.y, (float)mv[i + 1].y, rdB));
#endif
            mv[i + 1] = __builtin_elementwise_fma(
                w1p, __builtin_elementwise_fma(nev2, mv[i + 1], av2), mv[i + 1]);
        }
    }
}

// ---- recurrence: BB*2 two-wave blocks; w via LDS broadcast window ----
//  blk even -> roles {0,1}; blk odd -> roles {2, tail}; b = blk>>1.
//  Per group of 16 steps: all 128 threads issue 4 COALESCED Wh loads
//  (lane 0-31 = words 0-31 of one row, 4 rows per round), consume the
//  current LDS window (7 same-address ds_reads/step = HW broadcast),
//  then ds_write the next window and barrier. ea: depth-2 VMEM per-lane.
__global__ __launch_bounds__(128) void dkvmn_state(
        const int* __restrict__ qd, const int* __restrict__ qad,
        const u32* __restrict__ Wh, const u32* __restrict__ EA,
        const float* __restrict__ ivm, u16* __restrict__ READ) {
    const int tid  = threadIdx.x;          // 0..127
    const int lane = tid & 63;
    const int wid  = tid >> 6;             // 0,1
    const int blk  = blockIdx.x;
    const int b    = blk >> 1;
    const int role = (blk & 1) * 2 + wid;  // 0..3
    const int base = b * SS;

    __shared__ int qs[SS], qas[SS];              // 1.6 KB
    __shared__ u32 wlds[2][WGRP][WHS];           // 4 KB double-buffered window

    for (int i = tid; i < SS; i += 128) {
        qs[i]  = qd[base + i];
        qas[i] = qad[base + i];
    }
    __syncthreads();

    const int wword = tid & 31;            // word within Wh row
    const int wsub  = tid >> 5;            // 0..3: step-within-round

    // stage group 0 into wlds[0]
    {
        u32 w0s[4];
        #pragma unroll
        for (int r = 0; r < 4; ++r) {
            int s = r * 4 + wsub;
            int q = qs[(s < SS) ? s : (SS - 1)];
            w0s[r] = Wh[(size_t)q * WHS + wword];
        }
        #pragma unroll
        for (int r = 0; r < 4; ++r)
            wlds[0][r * 4 + wsub][wword] = w0s[r];
    }
    __syncthreads();

    if (role < 3) {
        // ---------------- heavy wave: 64 unique columns ----------------
        const int v = role * 64 + lane;    // < 192, every lane unique

        h2v mv[25];                        // pair i = slots (2i, 2i+1)
        #pragma unroll
        for (int i = 0; i < 25; ++i) {
            mv[i].x = (_Float16)ivm[(2 * i) * VD + v];
            mv[i].y = (_Float16)ivm[(2 * i + 1) * VD + v];
        }

        u32 ea_c = EA[(size_t)qas[0] * VD + v];
        u32 ea_n = EA[(size_t)qas[1] * VD + v];

        for (int g = 0; g < NG; ++g) {
            // issue next-group Wh loads early (coalesced, hidden under consume)
            u32 wstage[4];
            const bool do_stage = (g + 1 < NG);
            if (do_stage) {
                int s0 = (g + 1) * WGRP;
                #pragma unroll
                for (int r = 0; r < 4; ++r) {
                    int s = s0 + r * 4 + wsub;
                    int q = qs[(s < SS) ? s : (SS - 1)];
                    wstage[r] = Wh[(size_t)q * WHS + wword];
                }
            }

            const int nS = (g == NG - 1) ? (SS - WGRP * (NG - 1)) : WGRP;
            #pragma unroll 4
            for (int s = 0; s < nS; ++s) {
                const int t = g * WGRP + s;
                // w row t from LDS (same-address broadcast reads)
                const u32* wrow = &wlds[g & 1][s][0];
                u4v wr[6];
                #pragma unroll
                for (int j = 0; j < 6; ++j) wr[j] = *(const u4v*)(wrow + j * 4);
                u32 wr6 = wrow[24];

                // ea for t+2 (depth-2 pipeline, clamped)
                int t2 = t + 2; t2 = (t2 < SS) ? t2 : (SS - 1);
                u32 ea_f = EA[(size_t)qas[t2] * VD + v];

                float rdA, rdB;
                state_step_v(wr, wr6, ea_c, mv, rdA, rdB);
                READ[(size_t)(base + t) * VD + v] = f_to_bfu16(rdA + rdB);

                ea_c = ea_n; ea_n = ea_f;
            }

            if (do_stage) {
                #pragma unroll
                for (int r = 0; r < 4; ++r)
                    wlds[(g + 1) & 1][r * 4 + wsub][wword] = wstage[r];
            }
            __syncthreads();
        }
    } else {
        // ---------------- tail wave: v = 192..199, 8 slot-groups ----------------
        const int v8  = lane & 7;
        const int grp = lane >> 3;         // owns pairs grp*4 .. grp*4+3
        const int v   = 192 + v8;

        h2v mv4[4];
        #pragma unroll
        for (int j = 0; j < 4; ++j) {
            int p = grp * 4 + j;
            if (p < 25) {
                mv4[j].x = (_Float16)ivm[(2 * p) * VD + v];
                mv4[j].y = (_Float16)ivm[(2 * p + 1) * VD + v];
            } else {                       // padded pairs: w=0 keeps them 0
                mv4[j].x = (_Float16)0.f;
                mv4[j].y = (_Float16)0.f;
            }
        }

        u32 ea_c = EA[(size_t)qas[0] * VD + v];
        u32 ea_n = EA[(size_t)qas[1] * VD + v];

        for (int g = 0; g < NG; ++g) {
            u32 wstage[4];
            const bool do_stage = (g + 1 < NG);
            if (do_stage) {
                int s0 = (g + 1) * WGRP;
                #pragma unroll
                for (int r = 0; r < 4; ++r) {
                    int s = s0 + r * 4 + wsub;
                    int q = qs[(s < SS) ? s : (SS - 1)];
                    wstage[r] = Wh[(size_t)q * WHS + wword];
                }
            }

            const int nS = (g == NG - 1) ? (SS - WGRP * (NG - 1)) : WGRP;
            #pragma unroll 4
            for (int s = 0; s < nS; ++s) {
                const int t = g * WGRP + s;
                u4v wq = *(const u4v*)(&wlds[g & 1][s][grp * 4]);

                int t2 = t + 2; t2 = (t2 < SS) ? t2 : (SS - 1);
                u32 ea_f = EA[(size_t)qas[t2] * VD + v];

                h2v nev2 = u32_to_h2v(__builtin_amdgcn_perm(ea_c, ea_c, 0x01000100u));
                h2v av2  = u32_to_h2v(__builtin_amdgcn_perm(ea_c, ea_c, 0x03020302u));

                float rd = 0.f;
                #pragma unroll
                for (int j = 0; j < 4; ++j) {
                    h2v w2 = u32_to_h2v(wq[j]);
#if __has_builtin(__builtin_amdgcn_fdot2)
                    rd = __builtin_amdgcn_fdot2(w2, mv4[j], rd, false);
#else
                    rd = fmaf((float)w2.x, (float)mv4[j].x,
                         fmaf((float)w2.y, (float)mv4[j].y, rd));
#endif
                    mv4[j] = __builtin_elementwise_fma(
                        w2, __builtin_elementwise_fma(nev2, mv4[j], av2), mv4[j]);
                }
                // reduce over the 8 slot-groups (lane stride 8)
                rd += __shfl_xor(rd, 8, 64);
                rd += __shfl_xor(rd, 16, 64);
                rd += __shfl_xor(rd, 32, 64);
                if (grp == 0)
                    READ[(size_t)(base + t) * VD + v] = f_to_bfu16(rd);

                ea_c = ea_n; ea_n = ea_f;
            }

            if (do_stage) {
                #pragma unroll
                for (int r = 0; r < 4; ++r)
                    wlds[(g + 1) & 1][r * 4 + wsub][wword] = wstage[r];
            }
            __syncthreads();
        }
    }
}

// ---- prediction MLP via MFMA: per wave one 16-row strip, K=224, N=64 ----
__global__ __launch_bounds__(256) void mlp_pred(
        const u16* __restrict__ RD, const int* __restrict__ qd,
        const float* __restrict__ Q1tab, const u16* __restrict__ W1s,
        const float* __restrict__ w2, const float* __restrict__ b2,
        float* __restrict__ out) {
    const int tid  = threadIdx.x;
    const int lane = tid & 63;
    const int wv   = tid >> 6;
    const int strip = blockIdx.x * 4 + wv;
    const int row0  = strip * 16;

    const int mrow = lane & 15;        // A row within strip / C-D col (feature)
    const int quad = lane >> 4;

    s8v a[7];
    {
        const u16* arow = RD + (size_t)(row0 + mrow) * VD + quad * 8;
        #pragma unroll
        for (int kt = 0; kt < 7; ++kt)
            a[kt] = *(const s8v*)(arow + kt * 32);   // k>=200 garbage * B=0
    }

    const float b2f = b2[0];
    float pf[4] = {0.f, 0.f, 0.f, 0.f};

    #pragma unroll
    for (int nt = 0; nt < 4; ++nt) {
        s8v bfr[7];
        #pragma unroll
        for (int kt = 0; kt < 7; ++kt)
            bfr[kt] = *(const s8v*)(W1s + (((nt * 7 + kt) * 64) + lane) * 8);

        f4v acc = {0.f, 0.f, 0.f, 0.f};
        #pragma unroll
        for (int kt = 0; kt < 7; ++kt)
            acc = __builtin_amdgcn_mfma_f32_16x16x32_bf16(a[kt], bfr[kt], acc, 0, 0, 0);

        const int f = nt * 16 + mrow;                  // output feature col
        const float w2f = (f < FC) ? w2[f] : 0.f;
        #pragma unroll
        for (int r = 0; r < 4; ++r) {
            int row = row0 + quad * 4 + r;
            float h = acc[r] + Q1tab[qd[row] * FC + f];
            pf[r] = fmaf(fast_tanh(h), w2f, pf[r]);
        }
    }

    #pragma unroll
    for (int r = 0; r < 4; ++r) {
        float s = pf[r];
        s += __shfl_xor(s, 1, 64);
        s += __shfl_xor(s, 2, 64);
        s += __shfl_xor(s, 4, 64);
        s += __shfl_xor(s, 8, 64);
        if (mrow == 0)
            out[row0 + quad * 4 + r] = fast_sigmoid(s + b2f);
    }
}

// ---- fallback (barrier version, f32) if workspace too small ----
__global__ void dkvmn_main(const int* __restrict__ qd, const int* __restrict__ qad,
                           const float* __restrict__ Wtab, const float* __restrict__ Q1tab,
                           const u32* __restrict__ EA,
                           const float* __restrict__ ivm,
                           const float* __restrict__ w1,
                           const float* __restrict__ w2,
                           const float* __restrict__ b2,
                           float* __restrict__ out) {
    const int tid  = threadIdx.x;
    const int b    = blockIdx.x;
    const int v    = tid;
    const int lane = tid & 63;
    const int wv   = tid >> 6;

    __shared__ alignas(16) float read_lds[4 * 52];
    __shared__ alignas(16) float part_lds[4 * 52];

    float mv[MEMN];
    if (v < VD) {
        #pragma unroll
        for (int m = 0; m < MEMN; ++m) mv[m] = ivm[m * VD + v];
    }
    float w1r[50];
    if (lane < FC) {
        #pragma unroll
        for (int i = 0; i < 50; ++i) w1r[i] = w1[(wv * 50 + i) * FC + lane];
    } else {
        #pragma unroll
        for (int i = 0; i < 50; ++i) w1r[i] = 0.f;
    }
    const float w2f = (tid < FC) ? w2[tid] : 0.f;
    const float b2f = b2[0];

    const int* qrow_i  = qd  + b * SS;
    const int* qarow_i = qad + b * SS;
    const int jchunk = v / 50;
    const int wslot  = jchunk * 52 + (v - jchunk * 50);

    for (int t = 0; t < SS; ++t) {
        const int q  = __builtin_amdgcn_readfirstlane(qrow_i[t]);
        const int qa = __builtin_amdgcn_readfirstlane(qarow_i[t]);
        const float* wrow = Wtab + q * MEMN;

        u32 ea = 0;
        if (v < VD) ea = EA[(size_t)qa * VD + v];
        float ne = h16_to_f((u16)(ea & 0xffffu));   // -e
        float av = h16_to_f((u16)(ea >> 16));       //  a

        if (v < VD) {
            float rd0 = 0.f, rd1 = 0.f;
            #pragma unroll
            for (int m = 0; m < MEMN; m += 2) {
                float wm0 = wrow[m], wm1 = wrow[m + 1];
                rd0 = fmaf(wm0, mv[m], rd0);
                mv[m] = fmaf(wm0, fmaf(ne, mv[m], av), mv[m]);
                rd1 = fmaf(wm1, mv[m + 1], rd1);
                mv[m + 1] = fmaf(wm1, fmaf(ne, mv[m + 1], av), mv[m + 1]);
            }
            read_lds[wslot] = rd0 + rd1;
        }
        __syncthreads();

        float part = 0.f;
        {
            const float* rlc = read_lds + wv * 52;
            #pragma unroll
            for (int i = 0; i < 48; i += 4) {
                float4 x = *(const float4*)(rlc + i);
                part = fmaf(x.x, w1r[i],     part);
                part = fmaf(x.y, w1r[i + 1], part);
                part = fmaf(x.z, w1r[i + 2], part);
                part = fmaf(x.w, w1r[i + 3], part);
            }
            part = fmaf(rlc[48], w1r[48], part);
            part = fmaf(rlc[49], w1r[49], part);
        }
        if (lane < FC) part_lds[wv * 52 + lane] = part;
        __syncthreads();

        if (wv == 0) {
            float pf = 0.f;
            if (lane < FC) {
                float h = part_lds[lane] + part_lds[52 + lane] +
                          part_lds[104 + lane] + part_lds[156 + lane] +
                          Q1tab[q * FC + lane];
                pf = fast_tanh(h) * w2f;
            }
            #pragma unroll
            for (int off = 32; off >= 1; off >>= 1) pf += __shfl_xor(pf, off, 64);
            if (lane == 0) out[b * SS + t] = fast_sigmoid(pf + b2f);
        }
    }
}

extern "C" void kernel_launch(void* const* d_in, const int* in_sizes, int n_in,
                              void* d_out, int out_size, void* d_ws, size_t ws_size,
                              hipStream_t stream) {
    const int* qd  = (const int*)d_in[0];
    const int* qad = (const int*)d_in[1];
    const float* qemb  = (const float*)d_in[2];
    const float* qaemb = (const float*)d_in[3];
    const float* km    = (const float*)d_in[4];
    const float* ivm   = (const float*)d_in[5];
    const float* ew    = (const float*)d_in[6];
    const float* eb    = (const float*)d_in[7];
    const float* aw    = (const float*)d_in[8];
    const float* ab    = (const float*)d_in[9];
    const float* w1    = (const float*)d_in[10];
    const float* b1    = (const float*)d_in[11];
    const float* w2    = (const float*)d_in[12];
    const float* b2    = (const float*)d_in[13];
    float* out = (float*)d_out;
    (void)in_sizes; (void)n_in; (void)out_size;

    char* ws = (char*)d_ws;
    float* Wt  = (float*)(ws);                       // 1,000,200 -> pad 1,000,448
    float* Q1  = (float*)(ws + 1000448);             // 1,000,200 -> pad 1,000,448
    u32*   EA  = (u32*)  (ws + 2000896);             // 8,000,800 -> pad 8,001,024
    u16*   W1s = (u16*)  (ws + 10001920);            // 28,672    -> pad 32,768
    u32*   Wh  = (u32*)  (ws + 10034688);            // 640,128   -> pad 640,512
    u16*   RD  = (u16*)  (ws + 10675200);            // 163,840,000
    const size_t need = 10675200ull + 163840000ull + 512ull;

    // prep: EA + Wt/Wh/Q1 + W1s + zero outputs 1..3 (one dispatch)
    prep<<<PREP_G, 256, 0, stream>>>(qemb, km, w1, b1, qaemb, ew, eb, aw, ab,
                                     Wt, Wh, Q1, EA, W1s, out + (size_t)BB * SS);

    if (ws_size >= need) {
        dkvmn_state<<<BB * 2, 128, 0, stream>>>(qd, qad, Wh, EA, ivm, RD);
        mlp_pred<<<(BB * SS) / 64, 256, 0, stream>>>(RD, qd, Q1, W1s, w2, b2, out);
    } else {
        dkvmn_main<<<BB, 256, 0, stream>>>(qd, qad, Wt, Q1, EA, ivm, w1, w2, b2, out);
    }
}